// Round 1
// baseline (1602.328 us; speedup 1.0000x reference)
//
#include <hip/hip_runtime.h>
#include <math.h>

#define NPIX 4096
#define CCH 256

// ---------------- GroupNorm stats: 32 blocks = (b, g) ----------------
__global__ __launch_bounds__(256) void gn_stats_kernel(
    const float* __restrict__ x, const float* __restrict__ gn_w, const float* __restrict__ gn_b,
    float* __restrict__ alpha, float* __restrict__ beta)
{
  const int blk = blockIdx.x;           // 0..31
  const int b = blk >> 3, g = blk & 7;
  const float4* base = (const float4*)(x + (size_t)(b * CCH + g * 32) * NPIX);
  // 32 channels * 4096 pix = 131072 floats = 32768 float4 (contiguous)
  double s = 0.0, ss = 0.0;
  for (int idx = threadIdx.x; idx < 32768; idx += 256) {
    float4 v = base[idx];
    s  += (double)v.x + (double)v.y + (double)v.z + (double)v.w;
    ss += (double)v.x * v.x + (double)v.y * v.y + (double)v.z * v.z + (double)v.w * v.w;
  }
  __shared__ double rs[256], rss[256];
  rs[threadIdx.x] = s; rss[threadIdx.x] = ss;
  __syncthreads();
  for (int off = 128; off > 0; off >>= 1) {
    if (threadIdx.x < off) { rs[threadIdx.x] += rs[threadIdx.x + off]; rss[threadIdx.x] += rss[threadIdx.x + off]; }
    __syncthreads();
  }
  __shared__ float smean, srstd;
  if (threadIdx.x == 0) {
    double mean = rs[0] / 131072.0;
    double var  = rss[0] / 131072.0 - mean * mean;
    smean = (float)mean;
    srstd = (float)(1.0 / sqrt(var + 1e-5));
  }
  __syncthreads();
  if (threadIdx.x < 32) {
    int c = g * 32 + threadIdx.x;
    float a = srstd * gn_w[c];
    alpha[b * CCH + c] = a;
    beta [b * CCH + c] = gn_b[c] - smean * a;
  }
}

// ---------------- Tiled fp32 GEMM: out[b][m][n] = W[m][k] * X[b][k][n] + bias[m] (+resid) --------
// X optionally transformed per-channel: x*alpha[b*K+k] + beta[b*K+k]   (GroupNorm fold)
__global__ __launch_bounds__(256) void gemm64_kernel(
    const float* __restrict__ W, const float* __restrict__ bias,
    const float* __restrict__ X, const float* __restrict__ alpha, const float* __restrict__ beta,
    const float* __restrict__ resid, float* __restrict__ out, int M, int K)
{
  const int N = NPIX;
  const int b  = blockIdx.z;
  const int n0 = blockIdx.x * 64, m0 = blockIdx.y * 64;
  const float* Xb = X + (size_t)b * K * N;
  float* Ob = out + (size_t)b * M * N;

  __shared__ float Ws[16][68];   // [k][m], pad 68 (272B rows, 16B aligned)
  __shared__ float Xs[16][64];   // [k][n]

  const int tid = threadIdx.x;
  const int tx = tid & 15, ty = tid >> 4;
  float acc[4][4];
#pragma unroll
  for (int i = 0; i < 4; ++i)
#pragma unroll
    for (int j = 0; j < 4; ++j) acc[i][j] = 0.f;

  const float* ab_a = alpha ? alpha + b * K : nullptr;
  const float* ab_b = beta  ? beta  + b * K : nullptr;

  for (int k0 = 0; k0 < K; k0 += 16) {
    {
      int kk = tid & 15, mm = tid >> 4;
#pragma unroll
      for (int q = 0; q < 4; ++q)
        Ws[kk][mm + 16 * q] = W[(size_t)(m0 + mm + 16 * q) * K + k0 + kk];
    }
    {
      int nn = tid & 63, kb = tid >> 6;
#pragma unroll
      for (int q = 0; q < 4; ++q) {
        int krow = kb + 4 * q;
        float v = Xb[(size_t)(k0 + krow) * N + n0 + nn];
        if (ab_a) { int c = k0 + krow; v = v * ab_a[c] + ab_b[c]; }
        Xs[krow][nn] = v;
      }
    }
    __syncthreads();
#pragma unroll
    for (int kk = 0; kk < 16; ++kk) {
      float4 wv = *(const float4*)&Ws[kk][4 * ty];
      float4 xv = *(const float4*)&Xs[kk][4 * tx];
      acc[0][0] += wv.x * xv.x; acc[0][1] += wv.x * xv.y; acc[0][2] += wv.x * xv.z; acc[0][3] += wv.x * xv.w;
      acc[1][0] += wv.y * xv.x; acc[1][1] += wv.y * xv.y; acc[1][2] += wv.y * xv.z; acc[1][3] += wv.y * xv.w;
      acc[2][0] += wv.z * xv.x; acc[2][1] += wv.z * xv.y; acc[2][2] += wv.z * xv.z; acc[2][3] += wv.z * xv.w;
      acc[3][0] += wv.w * xv.x; acc[3][1] += wv.w * xv.y; acc[3][2] += wv.w * xv.z; acc[3][3] += wv.w * xv.w;
    }
    __syncthreads();
  }

#pragma unroll
  for (int i = 0; i < 4; ++i) {
    int row = m0 + 4 * ty + i;
    float bs = bias[row];
    size_t off = (size_t)row * N + n0 + 4 * tx;
    float4 o;
    o.x = acc[i][0] + bs; o.y = acc[i][1] + bs; o.z = acc[i][2] + bs; o.w = acc[i][3] + bs;
    if (resid) {
      float4 rv = *(const float4*)(resid + (size_t)b * M * N + off);
      o.x += rv.x; o.y += rv.y; o.z += rv.z; o.w += rv.w;
    }
    *(float4*)(Ob + off) = o;
  }
}

// ---------------- Flash attention: block = (i-tile 64, head, batch) ----------------
// qkv layout: [b][768][4096]; q rows 0..255, k rows 256..511, v rows 512..767 (per b).
// attn[i][j] = softmax_j( sum_d q[d][i] k[d][j] * 0.125 );  out[d][i] = sum_j attn[i][j] v[d][j]
__global__ __launch_bounds__(256) void attn_kernel(
    const float* __restrict__ qkv, float* __restrict__ out)
{
  const int b = blockIdx.z, h = blockIdx.y;
  const int i0 = blockIdx.x * 64;
  const int tid = threadIdx.x;
  const size_t bh = ((size_t)b * 768 + h * 64) * NPIX;
  const float* Q = qkv + bh;
  const float* K = qkv + bh + (size_t)256 * NPIX;
  const float* V = qkv + bh + (size_t)512 * NPIX;

  __shared__ float Ks[64 * 64];      // [d][j]
  __shared__ float Vs[64 * 65];      // [j][d] padded; reused as O[d][i] pad65 in epilogue
  __shared__ float Ps[64 * 64];      // [j][i]
  __shared__ float red[4 * 64];
  __shared__ float mbuf[64], lbuf[64], albuf[64];

  const int i  = tid & 63;   // S-phase row (also PV-phase d)
  const int jj = tid >> 6;   // 0..3

  // Q column for row i, scale folded in
  float qreg[64];
#pragma unroll
  for (int dd = 0; dd < 64; ++dd)
    qreg[dd] = Q[(size_t)dd * NPIX + i0 + i] * 0.125f;

  float oacc[16];
#pragma unroll
  for (int r = 0; r < 16; ++r) oacc[r] = 0.f;
  if (tid < 64) { mbuf[tid] = -1e30f; lbuf[tid] = 0.f; }
  __syncthreads();

  for (int j0 = 0; j0 < NPIX; j0 += 64) {
    // stage K,V tiles
    {
      const int jc = tid & 63, db = (tid >> 6) * 16;
#pragma unroll
      for (int q = 0; q < 16; ++q) {
        int dd = db + q;
        float kv = K[(size_t)dd * NPIX + j0 + jc];
        float vv = V[(size_t)dd * NPIX + j0 + jc];
        Ks[dd * 64 + jc] = kv;
        Vs[jc * 65 + dd] = vv;
      }
    }
    __syncthreads();

    // S = Q^T K for this thread's (i, 16 j's)
    float s[16];
#pragma unroll
    for (int r = 0; r < 16; ++r) s[r] = 0.f;
#pragma unroll
    for (int dd = 0; dd < 64; ++dd) {
      float qd = qreg[dd];
      const float4* k4 = (const float4*)(Ks + dd * 64 + jj * 16);
      float4 k0v = k4[0], k1v = k4[1], k2v = k4[2], k3v = k4[3];
      s[0]  += qd * k0v.x; s[1]  += qd * k0v.y; s[2]  += qd * k0v.z; s[3]  += qd * k0v.w;
      s[4]  += qd * k1v.x; s[5]  += qd * k1v.y; s[6]  += qd * k1v.z; s[7]  += qd * k1v.w;
      s[8]  += qd * k2v.x; s[9]  += qd * k2v.y; s[10] += qd * k2v.z; s[11] += qd * k2v.w;
      s[12] += qd * k3v.x; s[13] += qd * k3v.y; s[14] += qd * k3v.z; s[15] += qd * k3v.w;
    }

    // tile row-max
    float tm = s[0];
#pragma unroll
    for (int r = 1; r < 16; ++r) tm = fmaxf(tm, s[r]);
    red[jj * 64 + i] = tm;
    __syncthreads();
    if (tid < 64) {
      float m_old = mbuf[tid];
      float m_new = fmaxf(m_old, fmaxf(fmaxf(red[tid], red[64 + tid]),
                                       fmaxf(red[128 + tid], red[192 + tid])));
      mbuf[tid] = m_new;
      albuf[tid] = __expf(m_old - m_new);
    }
    __syncthreads();

    // P = exp(S - m), write to LDS, partial row-sum
    float mi = mbuf[i];
    float psum = 0.f;
#pragma unroll
    for (int r = 0; r < 16; ++r) {
      float p = __expf(s[r] - mi);
      Ps[(jj * 16 + r) * 64 + i] = p;
      psum += p;
    }
    red[jj * 64 + i] = psum;
    __syncthreads();
    if (tid < 64)
      lbuf[tid] = lbuf[tid] * albuf[tid] + red[tid] + red[64 + tid] + red[128 + tid] + red[192 + tid];

    // PV: thread owns (d = i, 16 i-columns ib*16+r)
    {
      const int d = tid & 63, ib = tid >> 6;
#pragma unroll
      for (int r = 0; r < 16; ++r) oacc[r] *= albuf[ib * 16 + r];
#pragma unroll 4
      for (int j = 0; j < 64; ++j) {
        float vj = Vs[j * 65 + d];
        const float4* p4 = (const float4*)(Ps + j * 64 + ib * 16);
        float4 p0 = p4[0], p1 = p4[1], p2 = p4[2], p3 = p4[3];
        oacc[0]  += vj * p0.x; oacc[1]  += vj * p0.y; oacc[2]  += vj * p0.z; oacc[3]  += vj * p0.w;
        oacc[4]  += vj * p1.x; oacc[5]  += vj * p1.y; oacc[6]  += vj * p1.z; oacc[7]  += vj * p1.w;
        oacc[8]  += vj * p2.x; oacc[9]  += vj * p2.y; oacc[10] += vj * p2.z; oacc[11] += vj * p2.w;
        oacc[12] += vj * p3.x; oacc[13] += vj * p3.y; oacc[14] += vj * p3.z; oacc[15] += vj * p3.w;
      }
    }
    __syncthreads();
  }

  // epilogue: normalize by l, transpose via LDS (reuse Vs) for coalesced store
  {
    const int d = tid & 63, ib = tid >> 6;
#pragma unroll
    for (int r = 0; r < 16; ++r) {
      int ii = ib * 16 + r;
      Vs[d * 65 + ii] = oacc[r] / lbuf[ii];
    }
  }
  __syncthreads();
  {
    const int ic = tid & 63, db = (tid >> 6) * 16;
    float* O = out + ((size_t)b * CCH + h * 64) * NPIX;
#pragma unroll
    for (int q = 0; q < 16; ++q) {
      int dd = db + q;
      O[(size_t)dd * NPIX + i0 + ic] = Vs[dd * 65 + ic];
    }
  }
}

extern "C" void kernel_launch(void* const* d_in, const int* in_sizes, int n_in,
                              void* d_out, int out_size, void* d_ws, size_t ws_size,
                              hipStream_t stream)
{
  const float* x      = (const float*)d_in[0];
  const float* gn_w   = (const float*)d_in[1];
  const float* gn_b   = (const float*)d_in[2];
  const float* qkv_w  = (const float*)d_in[3];
  const float* qkv_b  = (const float*)d_in[4];
  const float* proj_w = (const float*)d_in[5];
  const float* proj_b = (const float*)d_in[6];
  float* out = (float*)d_out;

  float* ws      = (float*)d_ws;
  float* alpha   = ws;                         // 4*256
  float* beta    = ws + 1024;                  // 4*256
  float* qkvbuf  = ws + 2048;                  // 4*768*4096 = 12582912 floats
  float* attnout = qkvbuf + (size_t)4 * 768 * NPIX;  // 4*256*4096 floats
  // total ws use: ~67.1 MB

  gn_stats_kernel<<<32, 256, 0, stream>>>(x, gn_w, gn_b, alpha, beta);
  gemm64_kernel<<<dim3(64, 12, 4), 256, 0, stream>>>(qkv_w, qkv_b, x, alpha, beta,
                                                     nullptr, qkvbuf, 768, 256);
  attn_kernel<<<dim3(64, 4, 4), 256, 0, stream>>>(qkvbuf, attnout);
  gemm64_kernel<<<dim3(64, 4, 4), 256, 0, stream>>>(proj_w, proj_b, attnout, nullptr, nullptr,
                                                    x, out, 256, 256);
}

// Round 2
// 553.406 us; speedup vs baseline: 2.8954x; 2.8954x over previous
//
#include <hip/hip_runtime.h>
#include <math.h>

#define NPIX 4096
#define CCH 256

typedef __attribute__((ext_vector_type(4))) float f32x4;
typedef __attribute__((ext_vector_type(8))) short s16x8;

__device__ __forceinline__ short bf16_rne(float x) {
  union { float f; unsigned u; } c; c.f = x;
  unsigned r = c.u + 0x7FFF + ((c.u >> 16) & 1);
  return (short)(r >> 16);
}
__device__ __forceinline__ unsigned pack2(float a, float b) {
  return (unsigned)(unsigned short)bf16_rne(a) | ((unsigned)(unsigned short)bf16_rne(b) << 16);
}

// ---------------- GroupNorm stats: 32 blocks = (b, g) ----------------
__global__ __launch_bounds__(256) void gn_stats_kernel(
    const float* __restrict__ x, const float* __restrict__ gn_w, const float* __restrict__ gn_b,
    float* __restrict__ alpha, float* __restrict__ beta)
{
  const int blk = blockIdx.x;
  const int b = blk >> 3, g = blk & 7;
  const float4* base = (const float4*)(x + (size_t)(b * CCH + g * 32) * NPIX);
  double s = 0.0, ss = 0.0;
  for (int idx = threadIdx.x; idx < 32768; idx += 256) {
    float4 v = base[idx];
    s  += (double)v.x + (double)v.y + (double)v.z + (double)v.w;
    ss += (double)v.x * v.x + (double)v.y * v.y + (double)v.z * v.z + (double)v.w * v.w;
  }
  __shared__ double rs[256], rss[256];
  rs[threadIdx.x] = s; rss[threadIdx.x] = ss;
  __syncthreads();
  for (int off = 128; off > 0; off >>= 1) {
    if (threadIdx.x < off) { rs[threadIdx.x] += rs[threadIdx.x + off]; rss[threadIdx.x] += rss[threadIdx.x + off]; }
    __syncthreads();
  }
  __shared__ float smean, srstd;
  if (threadIdx.x == 0) {
    double mean = rs[0] / 131072.0;
    double var  = rss[0] / 131072.0 - mean * mean;
    smean = (float)mean;
    srstd = (float)(1.0 / sqrt(var + 1e-5));
  }
  __syncthreads();
  if (threadIdx.x < 32) {
    int c = g * 32 + threadIdx.x;
    float a = srstd * gn_w[c];
    alpha[b * CCH + c] = a;
    beta [b * CCH + c] = gn_b[c] - smean * a;
  }
}

// ---------------- Tiled fp32 GEMM (unchanged from round 1) --------
__global__ __launch_bounds__(256) void gemm64_kernel(
    const float* __restrict__ W, const float* __restrict__ bias,
    const float* __restrict__ X, const float* __restrict__ alpha, const float* __restrict__ beta,
    const float* __restrict__ resid, float* __restrict__ out, int M, int K)
{
  const int N = NPIX;
  const int b  = blockIdx.z;
  const int n0 = blockIdx.x * 64, m0 = blockIdx.y * 64;
  const float* Xb = X + (size_t)b * K * N;
  float* Ob = out + (size_t)b * M * N;

  __shared__ float Ws[16][68];
  __shared__ float Xs[16][64];

  const int tid = threadIdx.x;
  const int tx = tid & 15, ty = tid >> 4;
  float acc[4][4];
#pragma unroll
  for (int i = 0; i < 4; ++i)
#pragma unroll
    for (int j = 0; j < 4; ++j) acc[i][j] = 0.f;

  const float* ab_a = alpha ? alpha + b * K : nullptr;
  const float* ab_b = beta  ? beta  + b * K : nullptr;

  for (int k0 = 0; k0 < K; k0 += 16) {
    {
      int kk = tid & 15, mm = tid >> 4;
#pragma unroll
      for (int q = 0; q < 4; ++q)
        Ws[kk][mm + 16 * q] = W[(size_t)(m0 + mm + 16 * q) * K + k0 + kk];
    }
    {
      int nn = tid & 63, kb = tid >> 6;
#pragma unroll
      for (int q = 0; q < 4; ++q) {
        int krow = kb + 4 * q;
        float v = Xb[(size_t)(k0 + krow) * N + n0 + nn];
        if (ab_a) { int c = k0 + krow; v = v * ab_a[c] + ab_b[c]; }
        Xs[krow][nn] = v;
      }
    }
    __syncthreads();
#pragma unroll
    for (int kk = 0; kk < 16; ++kk) {
      float4 wv = *(const float4*)&Ws[kk][4 * ty];
      float4 xv = *(const float4*)&Xs[kk][4 * tx];
      acc[0][0] += wv.x * xv.x; acc[0][1] += wv.x * xv.y; acc[0][2] += wv.x * xv.z; acc[0][3] += wv.x * xv.w;
      acc[1][0] += wv.y * xv.x; acc[1][1] += wv.y * xv.y; acc[1][2] += wv.y * xv.z; acc[1][3] += wv.y * xv.w;
      acc[2][0] += wv.z * xv.x; acc[2][1] += wv.z * xv.y; acc[2][2] += wv.z * xv.z; acc[2][3] += wv.z * xv.w;
      acc[3][0] += wv.w * xv.x; acc[3][1] += wv.w * xv.y; acc[3][2] += wv.w * xv.z; acc[3][3] += wv.w * xv.w;
    }
    __syncthreads();
  }

#pragma unroll
  for (int i = 0; i < 4; ++i) {
    int row = m0 + 4 * ty + i;
    float bs = bias[row];
    size_t off = (size_t)row * N + n0 + 4 * tx;
    float4 o;
    o.x = acc[i][0] + bs; o.y = acc[i][1] + bs; o.z = acc[i][2] + bs; o.w = acc[i][3] + bs;
    if (resid) {
      float4 rv = *(const float4*)(resid + (size_t)b * M * N + off);
      o.x += rv.x; o.y += rv.y; o.z += rv.z; o.w += rv.w;
    }
    *(float4*)(Ob + off) = o;
  }
}

// ---------------- MFMA flash attention ----------------
// Block = 128 threads (2 waves). Wave w owns i-rows [iblk + w*64, +64).
// Computes S^T = K^T Q^T (mfma: A=K frags, B=Q frags) so that the C-layout
// column (lane&15) indexes i; softmax state is lane-uniform. PV computes
// O^T[d][i] = V * P (A=V frags, B=P frags), matching the [c][n] output layout.
// K/V/P live in fragment-ordered LDS (lane-contiguous 16B -> conflict-free
// ds_read_b128).
__global__ __launch_bounds__(128) void attn_mfma_kernel(
    const float* __restrict__ qkv, float* __restrict__ out)
{
  const int b = blockIdx.z, h = blockIdx.y;
  const int iblk = blockIdx.x * 128;
  const int tid = threadIdx.x;
  const int wave = tid >> 6, lane = tid & 63;
  const int n16 = lane & 15, quad = lane >> 4;

  const float* Q  = qkv + ((size_t)b * 768 + h * 64) * NPIX;
  const float* Kg = Q + (size_t)256 * NPIX;
  const float* Vg = Q + (size_t)512 * NPIX;

  __shared__ short Ks[8 * 512];      // 8 frags x 1KB (j-sub x kstep)
  __shared__ short Vs[8 * 512];      // 8 frags (d-sub x kstep_j)
  __shared__ short Ps[2][8 * 512];   // per-wave P fragments (i-sub x kstep_j)

  // ---- Q fragments in registers: B-op layout B^T[i][d], scale folded ----
  const int i0w = iblk + wave * 64;
  s16x8 qf[4][2];
#pragma unroll
  for (int isub = 0; isub < 4; ++isub)
#pragma unroll
    for (int ks = 0; ks < 2; ++ks) {
      int ig = i0w + isub * 16 + n16;
      s16x8 f;
#pragma unroll
      for (int t = 0; t < 8; ++t) {
        int d = ks * 32 + quad * 8 + t;
        f[t] = bf16_rne(Q[(size_t)d * NPIX + ig] * 0.125f);
      }
      qf[isub][ks] = f;
    }

  f32x4 ot[4][4];   // O^T tiles [dsub][isub]
#pragma unroll
  for (int a = 0; a < 4; ++a)
#pragma unroll
    for (int c = 0; c < 4; ++c) ot[a][c] = (f32x4){0.f, 0.f, 0.f, 0.f};
  float m_i[4] = {-1e30f, -1e30f, -1e30f, -1e30f};
  float l_i[4] = {0.f, 0.f, 0.f, 0.f};

  const float LOG2E = 1.44269504f;

  for (int j0 = 0; j0 < NPIX; j0 += 64) {
    __syncthreads();   // previous iter's frag reads done before restaging

    // ---- stage K tile (64d x 64j) into fragment-ordered LDS, bf16 ----
    {
      const int jc = (tid & 31) * 2;       // two consecutive j per thread
      const int dg = tid >> 5;             // 0..3
#pragma unroll
      for (int p = 0; p < 8; ++p) {
        int d0 = dg * 16 + 2 * p;
        float2 va = *(const float2*)&Kg[(size_t)d0 * NPIX + j0 + jc];
        float2 vb = *(const float2*)&Kg[(size_t)(d0 + 1) * NPIX + j0 + jc];
        int fbase = (d0 >> 5), t = d0 & 7, qrow = (d0 >> 3) & 3;
        int j1 = jc, j2 = jc + 1;
        *(unsigned*)&Ks[((j1 >> 4) * 2 + fbase) * 512 + ((qrow << 4) | (j1 & 15)) * 8 + t] = pack2(va.x, vb.x);
        *(unsigned*)&Ks[((j2 >> 4) * 2 + fbase) * 512 + ((qrow << 4) | (j2 & 15)) * 8 + t] = pack2(va.y, vb.y);
      }
    }
    // ---- stage V tile (64d x 64j), A-op layout V[d][j] ----
    {
      const int j = (tid & 31) * 2;
      const int dr = tid >> 5;             // 0..3
#pragma unroll
      for (int p = 0; p < 16; ++p) {
        int d = dr + 4 * p;
        float2 v = *(const float2*)&Vg[(size_t)d * NPIX + j0 + j];
        int g = (d >> 4) * 2 + (j >> 5);
        int L = (((j >> 3) & 3) << 4) | (d & 15);
        *(unsigned*)&Vs[g * 512 + L * 8 + (j & 7)] = pack2(v.x, v.y);
      }
    }
    __syncthreads();

    // ---- S^T = K^T Q^T ----
    f32x4 st[4][4];
#pragma unroll
    for (int a = 0; a < 4; ++a)
#pragma unroll
      for (int c = 0; c < 4; ++c) st[a][c] = (f32x4){0.f, 0.f, 0.f, 0.f};
#pragma unroll
    for (int ks = 0; ks < 2; ++ks)
#pragma unroll
      for (int jsub = 0; jsub < 4; ++jsub) {
        s16x8 a = *(const s16x8*)&Ks[(jsub * 2 + ks) * 512 + lane * 8];
#pragma unroll
        for (int isub = 0; isub < 4; ++isub)
          st[jsub][isub] = __builtin_amdgcn_mfma_f32_16x16x32_bf16(a, qf[isub][ks], st[jsub][isub], 0, 0, 0);
      }

    // ---- online softmax (per lane: column i = isub*16 + n16) ----
    float alpha_s[4];
#pragma unroll
    for (int isub = 0; isub < 4; ++isub) {
      float tm = st[0][isub][0];
#pragma unroll
      for (int jsub = 0; jsub < 4; ++jsub)
#pragma unroll
        for (int r = 0; r < 4; ++r) tm = fmaxf(tm, st[jsub][isub][r]);
      tm = fmaxf(tm, __shfl_xor(tm, 16));
      tm = fmaxf(tm, __shfl_xor(tm, 32));
      float mn = fmaxf(m_i[isub], tm);
      alpha_s[isub] = exp2f((m_i[isub] - mn) * LOG2E);
      m_i[isub] = mn;
      float ps = 0.f;
#pragma unroll
      for (int jsub = 0; jsub < 4; ++jsub)
#pragma unroll
        for (int r = 0; r < 4; ++r) {
          float p = exp2f((st[jsub][isub][r] - mn) * LOG2E);
          st[jsub][isub][r] = p;
          ps += p;
        }
      ps += __shfl_xor(ps, 16);
      ps += __shfl_xor(ps, 32);
      l_i[isub] = l_i[isub] * alpha_s[isub] + ps;
    }

    // ---- write P into PV B-fragment layout (wave-private region) ----
#pragma unroll
    for (int jsub = 0; jsub < 4; ++jsub)
#pragma unroll
      for (int isub = 0; isub < 4; ++isub) {
        unsigned lo = pack2(st[jsub][isub][0], st[jsub][isub][1]);
        unsigned hi = pack2(st[jsub][isub][2], st[jsub][isub][3]);
        int kstep = jsub >> 1;
        int quad_f = (jsub & 1) * 2 + (quad >> 1);
        int t0 = (quad & 1) * 4;
        uint2 w2; w2.x = lo; w2.y = hi;
        *(uint2*)&Ps[wave][(isub * 2 + kstep) * 512 + (quad_f * 16 + n16) * 8 + t0] = w2;
      }
    __syncthreads();   // P write -> P read (also covers nothing else)

    // ---- rescale O, then O^T += V * P ----
#pragma unroll
    for (int dsub = 0; dsub < 4; ++dsub)
#pragma unroll
      for (int isub = 0; isub < 4; ++isub)
#pragma unroll
        for (int r = 0; r < 4; ++r) ot[dsub][isub][r] *= alpha_s[isub];

#pragma unroll
    for (int ks = 0; ks < 2; ++ks) {
      s16x8 pb[4];
#pragma unroll
      for (int isub = 0; isub < 4; ++isub)
        pb[isub] = *(const s16x8*)&Ps[wave][(isub * 2 + ks) * 512 + lane * 8];
#pragma unroll
      for (int dsub = 0; dsub < 4; ++dsub) {
        s16x8 a = *(const s16x8*)&Vs[(dsub * 2 + ks) * 512 + lane * 8];
#pragma unroll
        for (int isub = 0; isub < 4; ++isub)
          ot[dsub][isub] = __builtin_amdgcn_mfma_f32_16x16x32_bf16(a, pb[isub], ot[dsub][isub], 0, 0, 0);
      }
    }
  }

  // ---- epilogue: normalize, store O^T directly in [c][n] layout ----
  float rl[4];
#pragma unroll
  for (int isub = 0; isub < 4; ++isub) rl[isub] = 1.0f / l_i[isub];
#pragma unroll
  for (int dsub = 0; dsub < 4; ++dsub)
#pragma unroll
    for (int isub = 0; isub < 4; ++isub) {
      int ig = i0w + isub * 16 + n16;
#pragma unroll
      for (int r = 0; r < 4; ++r) {
        int dgl = h * 64 + dsub * 16 + quad * 4 + r;
        out[((size_t)b * CCH + dgl) * NPIX + ig] = ot[dsub][isub][r] * rl[isub];
      }
    }
}

extern "C" void kernel_launch(void* const* d_in, const int* in_sizes, int n_in,
                              void* d_out, int out_size, void* d_ws, size_t ws_size,
                              hipStream_t stream)
{
  const float* x      = (const float*)d_in[0];
  const float* gn_w   = (const float*)d_in[1];
  const float* gn_b   = (const float*)d_in[2];
  const float* qkv_w  = (const float*)d_in[3];
  const float* qkv_b  = (const float*)d_in[4];
  const float* proj_w = (const float*)d_in[5];
  const float* proj_b = (const float*)d_in[6];
  float* out = (float*)d_out;

  float* ws      = (float*)d_ws;
  float* alpha   = ws;
  float* beta    = ws + 1024;
  float* qkvbuf  = ws + 2048;
  float* attnout = qkvbuf + (size_t)4 * 768 * NPIX;

  gn_stats_kernel<<<32, 256, 0, stream>>>(x, gn_w, gn_b, alpha, beta);
  gemm64_kernel<<<dim3(64, 12, 4), 256, 0, stream>>>(qkv_w, qkv_b, x, alpha, beta,
                                                     nullptr, qkvbuf, 768, 256);
  attn_mfma_kernel<<<dim3(32, 4, 4), 128, 0, stream>>>(qkvbuf, attnout);
  gemm64_kernel<<<dim3(64, 4, 4), 256, 0, stream>>>(proj_w, proj_b, attnout, nullptr, nullptr,
                                                    x, out, 256, 256);
}

// Round 3
// 355.504 us; speedup vs baseline: 4.5072x; 1.5567x over previous
//
#include <hip/hip_runtime.h>
#include <math.h>

#define NPIX 4096
#define CCH 256

typedef __attribute__((ext_vector_type(4))) float f32x4;
typedef __attribute__((ext_vector_type(8))) short s16x8;
typedef unsigned short u16;

__device__ __forceinline__ short bf16_rne(float x) {
  union { float f; unsigned u; } c; c.f = x;
  unsigned r = c.u + 0x7FFF + ((c.u >> 16) & 1);
  return (short)(r >> 16);
}
__device__ __forceinline__ unsigned pack2(float a, float b) {
  return (unsigned)(unsigned short)bf16_rne(a) | ((unsigned)(unsigned short)bf16_rne(b) << 16);
}

#define QSCALE 0.18033688011f   /* 0.125 * log2(e) */

// ---------------- GroupNorm stats: 32 blocks = (b, g) ----------------
__global__ __launch_bounds__(256) void gn_stats_kernel(
    const float* __restrict__ x, const float* __restrict__ gn_w, const float* __restrict__ gn_b,
    float* __restrict__ alpha, float* __restrict__ beta)
{
  const int blk = blockIdx.x;
  const int b = blk >> 3, g = blk & 7;
  const float4* base = (const float4*)(x + (size_t)(b * CCH + g * 32) * NPIX);
  double s = 0.0, ss = 0.0;
  for (int idx = threadIdx.x; idx < 32768; idx += 256) {
    float4 v = base[idx];
    s  += (double)v.x + (double)v.y + (double)v.z + (double)v.w;
    ss += (double)v.x * v.x + (double)v.y * v.y + (double)v.z * v.z + (double)v.w * v.w;
  }
  __shared__ double rs[256], rss[256];
  rs[threadIdx.x] = s; rss[threadIdx.x] = ss;
  __syncthreads();
  for (int off = 128; off > 0; off >>= 1) {
    if (threadIdx.x < off) { rs[threadIdx.x] += rs[threadIdx.x + off]; rss[threadIdx.x] += rss[threadIdx.x + off]; }
    __syncthreads();
  }
  __shared__ float smean, srstd;
  if (threadIdx.x == 0) {
    double mean = rs[0] / 131072.0;
    double var  = rss[0] / 131072.0 - mean * mean;
    smean = (float)mean;
    srstd = (float)(1.0 / sqrt(var + 1e-5));
  }
  __syncthreads();
  if (threadIdx.x < 32) {
    int c = g * 32 + threadIdx.x;
    float a = srstd * gn_w[c];
    alpha[b * CCH + c] = a;
    beta [b * CCH + c] = gn_b[c] - smean * a;
  }
}

// ---------------- Weight/bias convert: fp32 -> bf16, q rows pre-scaled ----------------
__global__ __launch_bounds__(256) void wcvt_kernel(
    const float* __restrict__ qkv_w, const float* __restrict__ proj_w, const float* __restrict__ qkv_b,
    u16* __restrict__ wq, u16* __restrict__ wp, float* __restrict__ biasq)
{
  int idx = blockIdx.x * 256 + threadIdx.x;   // 0..262143
  if (idx < 196608) {
    float v = qkv_w[idx];
    if (idx < 65536) v *= QSCALE;             // q rows (o < 256)
    wq[idx] = (u16)bf16_rne(v);
  } else {
    int j = idx - 196608;
    wp[j] = (u16)bf16_rne(proj_w[j]);
  }
  if (idx < 768) {
    float bv = qkv_b[idx];
    if (idx < 256) bv *= QSCALE;
    biasq[idx] = bv;
  }
}

// ---------------- GN apply + transpose: x[b][c][n] fp32 -> Xt[b][n][c] bf16 ----------------
__global__ __launch_bounds__(256) void gn_apply_t_kernel(
    const float* __restrict__ x, const float* __restrict__ alpha, const float* __restrict__ beta,
    u16* __restrict__ Xt)
{
  const int b = blockIdx.z, c0 = blockIdx.y * 64, n0 = blockIdx.x * 64;
  const int tid = threadIdx.x;
  __shared__ u16 T[64 * 68];
  const int n4 = (tid & 15) * 4, cr = tid >> 4;
#pragma unroll
  for (int p = 0; p < 4; ++p) {
    int cl = cr + 16 * p;
    int c = c0 + cl;
    float a = alpha[b * CCH + c], bt = beta[b * CCH + c];
    float4 v = *(const float4*)&x[((size_t)b * CCH + c) * NPIX + n0 + n4];
    T[(n4 + 0) * 68 + cl] = (u16)bf16_rne(v.x * a + bt);
    T[(n4 + 1) * 68 + cl] = (u16)bf16_rne(v.y * a + bt);
    T[(n4 + 2) * 68 + cl] = (u16)bf16_rne(v.z * a + bt);
    T[(n4 + 3) * 68 + cl] = (u16)bf16_rne(v.w * a + bt);
  }
  __syncthreads();
#pragma unroll
  for (int it = 0; it < 2; ++it) {
    int linear = it * 256 + tid;
    int n = linear >> 3, ch = linear & 7;
    s16x8 v = *(const s16x8*)&T[n * 68 + ch * 8];
    *(s16x8*)&Xt[((size_t)b * NPIX + n0 + n) * CCH + c0 + ch * 8] = v;
  }
}

// ---------------- QKV GEMM (bf16 MFMA): D[m][n] = W[m][k] Xt[n][k] + bias ----------------
// m-blocks 0..3 -> Qt[b][i][ch] (transposed store), 4..7 -> Kt, 8..11 -> V[b][c][n]
__global__ __launch_bounds__(256) void qkv_gemm_kernel(
    const u16* __restrict__ Wbf, const float* __restrict__ biasv, const u16* __restrict__ Xt,
    u16* __restrict__ Qt, u16* __restrict__ Kt, u16* __restrict__ Vb)
{
  const int nblk = blockIdx.x, m0 = blockIdx.y * 64;
  const int tid = threadIdx.x, wave = tid >> 6, lane = tid & 63;
  const int n16 = lane & 15, quad = lane >> 4;
  const int n0 = nblk * 128 + wave * 32;   // flat row (b*4096 + i)

  f32x4 acc[4][2];
#pragma unroll
  for (int a = 0; a < 4; ++a)
#pragma unroll
    for (int c = 0; c < 2; ++c) acc[a][c] = (f32x4){0.f, 0.f, 0.f, 0.f};

#pragma unroll
  for (int k0 = 0; k0 < 256; k0 += 32) {
    s16x8 af[4], bfr[2];
#pragma unroll
    for (int msub = 0; msub < 4; ++msub)
      af[msub] = *(const s16x8*)&Wbf[(size_t)(m0 + msub * 16 + n16) * 256 + k0 + quad * 8];
#pragma unroll
    for (int nsub = 0; nsub < 2; ++nsub)
      bfr[nsub] = *(const s16x8*)&Xt[(size_t)(n0 + nsub * 16 + n16) * 256 + k0 + quad * 8];
#pragma unroll
    for (int msub = 0; msub < 4; ++msub)
#pragma unroll
      for (int nsub = 0; nsub < 2; ++nsub)
        acc[msub][nsub] = __builtin_amdgcn_mfma_f32_16x16x32_bf16(af[msub], bfr[nsub], acc[msub][nsub], 0, 0, 0);
  }

  __shared__ u16 T[8704];   // qk: [n128][m 68]; v: [m64][n 136]
  if (m0 < 512) {
    // bias + pack, store transposed tile [n][m]
#pragma unroll
    for (int msub = 0; msub < 4; ++msub)
#pragma unroll
      for (int nsub = 0; nsub < 2; ++nsub) {
        float b0 = biasv[m0 + msub * 16 + quad * 4 + 0];
        float b1 = biasv[m0 + msub * 16 + quad * 4 + 1];
        float b2 = biasv[m0 + msub * 16 + quad * 4 + 2];
        float b3 = biasv[m0 + msub * 16 + quad * 4 + 3];
        uint2 w2;
        w2.x = pack2(acc[msub][nsub][0] + b0, acc[msub][nsub][1] + b1);
        w2.y = pack2(acc[msub][nsub][2] + b2, acc[msub][nsub][3] + b3);
        *(uint2*)&T[(wave * 32 + nsub * 16 + n16) * 68 + msub * 16 + quad * 4] = w2;
      }
    __syncthreads();
    u16* dst = (m0 < 256) ? Qt : Kt;
    const int coff = m0 & 255;
#pragma unroll
    for (int it = 0; it < 4; ++it) {
      int linear = it * 256 + tid;
      int n = linear >> 3, ch = linear & 7;
      s16x8 v = *(const s16x8*)&T[n * 68 + ch * 8];
      *(s16x8*)&dst[(size_t)(nblk * 128 + n) * 256 + coff + ch * 8] = v;
    }
  } else {
    // V: store [m][n] natural rows
#pragma unroll
    for (int msub = 0; msub < 4; ++msub)
#pragma unroll
      for (int nsub = 0; nsub < 2; ++nsub) {
        int ncol = wave * 32 + nsub * 16 + n16;
#pragma unroll
        for (int r = 0; r < 4; ++r) {
          int m = msub * 16 + quad * 4 + r;
          T[m * 136 + ncol] = (u16)bf16_rne(acc[msub][nsub][r] + biasv[m0 + m]);
        }
      }
    __syncthreads();
    const int b = (nblk * 128) >> 12, i0n = (nblk * 128) & 4095;
#pragma unroll
    for (int it = 0; it < 4; ++it) {
      int linear = it * 256 + tid;
      int mloc = linear >> 4, ch = linear & 15;
      s16x8 v = *(const s16x8*)&T[mloc * 136 + ch * 8];
      int c = (m0 - 512) + mloc;
      *(s16x8*)&Vb[((size_t)b * CCH + c) * NPIX + i0n + ch * 8] = v;
    }
  }
}

// ---------------- MFMA flash attention, shared-staged K/V, no-conflict copies ----------------
// Block = 128 threads (2 waves); wave owns 32 i-rows. Grid (64, 4, 4).
__global__ __launch_bounds__(128) void attn_kernel2(
    const u16* __restrict__ Qt, const u16* __restrict__ Kt,
    const u16* __restrict__ Vb, u16* __restrict__ Ot)
{
  const int b = blockIdx.z, h = blockIdx.y;
  const int tid = threadIdx.x;
  const int wave = tid >> 6, lane = tid & 63;
  const int n16 = lane & 15, quad = lane >> 4;
  const int i0w = blockIdx.x * 64 + wave * 32;

  __shared__ u16 Ks[8 * 520];
  __shared__ u16 Vs[8 * 520];
  __shared__ u16 Ps[2][4 * 512];

  const u16* Qb = Qt + (size_t)b * NPIX * 256;
  const u16* Kb = Kt + (size_t)b * NPIX * 256;
  const u16* Vg = Vb + ((size_t)b * CCH + h * 64) * NPIX;

  // Q fragments (B-op: lane holds i=n16, 8 consecutive d)
  s16x8 qf[2][2];
#pragma unroll
  for (int isub = 0; isub < 2; ++isub)
#pragma unroll
    for (int ks = 0; ks < 2; ++ks)
      qf[isub][ks] = *(const s16x8*)&Qb[(size_t)(i0w + isub * 16 + n16) * 256 + h * 64 + ks * 32 + quad * 8];

  f32x4 ot[4][2];
#pragma unroll
  for (int a = 0; a < 4; ++a)
#pragma unroll
    for (int c = 0; c < 2; ++c) ot[a][c] = (f32x4){0.f, 0.f, 0.f, 0.f};
  float m_i[2] = {-1e30f, -1e30f};
  float l_i[2] = {0.f, 0.f};

  const int sj = tid >> 1;     // row index within tile (j for K, d for V)
  const int sh = tid & 1;      // which 32-channel half
  const int sfrag = (sj >> 4) * 2 + sh;
  const int slot = sj & 15;

  for (int j0 = 0; j0 < NPIX; j0 += 64) {
    // global loads first (overlap with barrier wait)
    const s16x8* kp = (const s16x8*)&Kb[(size_t)(j0 + sj) * 256 + h * 64 + sh * 32];
    const s16x8* vp = (const s16x8*)&Vg[(size_t)sj * NPIX + j0 + sh * 32];
    s16x8 k0 = kp[0], k1 = kp[1], k2 = kp[2], k3 = kp[3];
    s16x8 v0 = vp[0], v1 = vp[1], v2 = vp[2], v3 = vp[3];
    __syncthreads();   // previous iter's fragment reads complete
    *(s16x8*)&Ks[sfrag * 520 + (0 * 16 + slot) * 8] = k0;
    *(s16x8*)&Ks[sfrag * 520 + (1 * 16 + slot) * 8] = k1;
    *(s16x8*)&Ks[sfrag * 520 + (2 * 16 + slot) * 8] = k2;
    *(s16x8*)&Ks[sfrag * 520 + (3 * 16 + slot) * 8] = k3;
    *(s16x8*)&Vs[sfrag * 520 + (0 * 16 + slot) * 8] = v0;
    *(s16x8*)&Vs[sfrag * 520 + (1 * 16 + slot) * 8] = v1;
    *(s16x8*)&Vs[sfrag * 520 + (2 * 16 + slot) * 8] = v2;
    *(s16x8*)&Vs[sfrag * 520 + (3 * 16 + slot) * 8] = v3;
    __syncthreads();

    // S^T = K^T Q^T  (A=K frag: m=j, B=Q frag: n=i)
    f32x4 st[4][2];
#pragma unroll
    for (int a = 0; a < 4; ++a)
#pragma unroll
      for (int c = 0; c < 2; ++c) st[a][c] = (f32x4){0.f, 0.f, 0.f, 0.f};
#pragma unroll
    for (int ks = 0; ks < 2; ++ks)
#pragma unroll
      for (int jsub = 0; jsub < 4; ++jsub) {
        s16x8 a = *(const s16x8*)&Ks[(jsub * 2 + ks) * 520 + lane * 8];
#pragma unroll
        for (int isub = 0; isub < 2; ++isub)
          st[jsub][isub] = __builtin_amdgcn_mfma_f32_16x16x32_bf16(a, qf[isub][ks], st[jsub][isub], 0, 0, 0);
      }

    // online softmax in log2 domain (scale folded into Wq)
    float alpha_s[2];
#pragma unroll
    for (int isub = 0; isub < 2; ++isub) {
      float tm = st[0][isub][0];
#pragma unroll
      for (int jsub = 0; jsub < 4; ++jsub)
#pragma unroll
        for (int r = 0; r < 4; ++r) tm = fmaxf(tm, st[jsub][isub][r]);
      tm = fmaxf(tm, __shfl_xor(tm, 16));
      tm = fmaxf(tm, __shfl_xor(tm, 32));
      float mn = fmaxf(m_i[isub], tm);
      alpha_s[isub] = __builtin_amdgcn_exp2f(m_i[isub] - mn);
      m_i[isub] = mn;
      float ps = 0.f;
#pragma unroll
      for (int jsub = 0; jsub < 4; ++jsub)
#pragma unroll
        for (int r = 0; r < 4; ++r) {
          float p = __builtin_amdgcn_exp2f(st[jsub][isub][r] - mn);
          st[jsub][isub][r] = p;
          ps += p;
        }
      ps += __shfl_xor(ps, 16);
      ps += __shfl_xor(ps, 32);
      l_i[isub] = l_i[isub] * alpha_s[isub] + ps;
    }

    // P -> PV B-fragment layout (wave-private LDS; no barrier needed)
#pragma unroll
    for (int jsub = 0; jsub < 4; ++jsub)
#pragma unroll
      for (int isub = 0; isub < 2; ++isub) {
        uint2 w2;
        w2.x = pack2(st[jsub][isub][0], st[jsub][isub][1]);
        w2.y = pack2(st[jsub][isub][2], st[jsub][isub][3]);
        int addr = (isub * 2 + (jsub >> 1)) * 512 + (((jsub & 1) * 2 + (quad >> 1)) * 16 + n16) * 8 + (quad & 1) * 4;
        *(uint2*)&Ps[wave][addr] = w2;
      }

    // rescale O, then O^T += V * P
#pragma unroll
    for (int dsub = 0; dsub < 4; ++dsub)
#pragma unroll
      for (int isub = 0; isub < 2; ++isub)
#pragma unroll
        for (int r = 0; r < 4; ++r) ot[dsub][isub][r] *= alpha_s[isub];

#pragma unroll
    for (int ks = 0; ks < 2; ++ks) {
      s16x8 pb0 = *(const s16x8*)&Ps[wave][(0 + ks) * 512 + lane * 8];
      s16x8 pb1 = *(const s16x8*)&Ps[wave][(2 + ks) * 512 + lane * 8];
#pragma unroll
      for (int dsub = 0; dsub < 4; ++dsub) {
        s16x8 a = *(const s16x8*)&Vs[(dsub * 2 + ks) * 520 + lane * 8];
        ot[dsub][0] = __builtin_amdgcn_mfma_f32_16x16x32_bf16(a, pb0, ot[dsub][0], 0, 0, 0);
        ot[dsub][1] = __builtin_amdgcn_mfma_f32_16x16x32_bf16(a, pb1, ot[dsub][1], 0, 0, 0);
      }
    }
  }

  // epilogue: normalize, store O^T rows into Ot[b][i][ch] bf16
  float rl[2] = {1.0f / l_i[0], 1.0f / l_i[1]};
#pragma unroll
  for (int dsub = 0; dsub < 4; ++dsub)
#pragma unroll
    for (int isub = 0; isub < 2; ++isub) {
      uint2 w2;
      w2.x = pack2(ot[dsub][isub][0] * rl[isub], ot[dsub][isub][1] * rl[isub]);
      w2.y = pack2(ot[dsub][isub][2] * rl[isub], ot[dsub][isub][3] * rl[isub]);
      size_t addr = (size_t)((size_t)b * NPIX + i0w + isub * 16 + n16) * 256 + h * 64 + dsub * 16 + quad * 4;
      *(uint2*)&Ot[addr] = w2;
    }
}

// ---------------- Proj GEMM (bf16 MFMA) + bias + residual, fp32 out ----------------
__global__ __launch_bounds__(256) void proj_gemm_kernel(
    const u16* __restrict__ Wp, const float* __restrict__ proj_b, const u16* __restrict__ Ot,
    const float* __restrict__ x, float* __restrict__ out)
{
  const int nblk = blockIdx.x, m0 = blockIdx.y * 64;
  const int tid = threadIdx.x, wave = tid >> 6, lane = tid & 63;
  const int n16 = lane & 15, quad = lane >> 4;
  const int n0 = nblk * 128 + wave * 32;

  f32x4 acc[4][2];
#pragma unroll
  for (int a = 0; a < 4; ++a)
#pragma unroll
    for (int c = 0; c < 2; ++c) acc[a][c] = (f32x4){0.f, 0.f, 0.f, 0.f};

#pragma unroll
  for (int k0 = 0; k0 < 256; k0 += 32) {
    s16x8 af[4], bfr[2];
#pragma unroll
    for (int msub = 0; msub < 4; ++msub)
      af[msub] = *(const s16x8*)&Wp[(size_t)(m0 + msub * 16 + n16) * 256 + k0 + quad * 8];
#pragma unroll
    for (int nsub = 0; nsub < 2; ++nsub)
      bfr[nsub] = *(const s16x8*)&Ot[(size_t)(n0 + nsub * 16 + n16) * 256 + k0 + quad * 8];
#pragma unroll
    for (int msub = 0; msub < 4; ++msub)
#pragma unroll
      for (int nsub = 0; nsub < 2; ++nsub)
        acc[msub][nsub] = __builtin_amdgcn_mfma_f32_16x16x32_bf16(af[msub], bfr[nsub], acc[msub][nsub], 0, 0, 0);
  }

  __shared__ float T[64 * 132];
#pragma unroll
  for (int msub = 0; msub < 4; ++msub)
#pragma unroll
    for (int nsub = 0; nsub < 2; ++nsub) {
      int ncol = wave * 32 + nsub * 16 + n16;
#pragma unroll
      for (int r = 0; r < 4; ++r) {
        int m = msub * 16 + quad * 4 + r;
        T[m * 132 + ncol] = acc[msub][nsub][r];
      }
    }
  __syncthreads();
  const int b = (nblk * 128) >> 12, i0n = (nblk * 128) & 4095;
#pragma unroll
  for (int it = 0; it < 8; ++it) {
    int linear = it * 256 + tid;
    int m = linear >> 5, ch = linear & 31;
    f32x4 v = *(const f32x4*)&T[m * 132 + ch * 4];
    float bs = proj_b[m0 + m];
    size_t g = ((size_t)b * CCH + m0 + m) * NPIX + i0n + ch * 4;
    float4 rv = *(const float4*)&x[g];
    float4 o;
    o.x = v[0] + bs + rv.x; o.y = v[1] + bs + rv.y;
    o.z = v[2] + bs + rv.z; o.w = v[3] + bs + rv.w;
    *(float4*)&out[g] = o;
  }
}

extern "C" void kernel_launch(void* const* d_in, const int* in_sizes, int n_in,
                              void* d_out, int out_size, void* d_ws, size_t ws_size,
                              hipStream_t stream)
{
  const float* x      = (const float*)d_in[0];
  const float* gn_w   = (const float*)d_in[1];
  const float* gn_b   = (const float*)d_in[2];
  const float* qkv_w  = (const float*)d_in[3];
  const float* qkv_b  = (const float*)d_in[4];
  const float* proj_w = (const float*)d_in[5];
  const float* proj_b = (const float*)d_in[6];
  float* out = (float*)d_out;

  float* ws    = (float*)d_ws;
  float* alpha = ws;                       // 1024
  float* beta  = ws + 1024;                // 1024
  float* biasq = ws + 2048;                // 768 (pad to 2048)
  u16*   wq    = (u16*)(ws + 4096);        // 196608 shorts = 98304 floats
  u16*   wp    = (u16*)(ws + 102400);      // 65536 shorts = 32768 floats
  u16*   Xt    = (u16*)(ws + 135168);      // 4*4096*256 shorts = 2097152 floats
  u16*   Qt    = (u16*)(ws + 2232320);
  u16*   Kt    = (u16*)(ws + 4329472);
  u16*   Vb    = (u16*)(ws + 6426624);
  u16*   Ot    = (u16*)(ws + 8523776);     // end at 10620928 floats (~42.5 MB)

  gn_stats_kernel<<<32, 256, 0, stream>>>(x, gn_w, gn_b, alpha, beta);
  wcvt_kernel<<<1024, 256, 0, stream>>>(qkv_w, proj_w, qkv_b, wq, wp, biasq);
  gn_apply_t_kernel<<<dim3(64, 4, 4), 256, 0, stream>>>(x, alpha, beta, Xt);
  qkv_gemm_kernel<<<dim3(128, 12), 256, 0, stream>>>(wq, biasq, Xt, Qt, Kt, Vb);
  attn_kernel2<<<dim3(64, 4, 4), 128, 0, stream>>>(Qt, Kt, Vb, Ot);
  proj_gemm_kernel<<<dim3(128, 4), 256, 0, stream>>>(wp, proj_b, Ot, x, out);
}